// Round 19
// baseline (198.445 us; speedup 1.0000x reference)
//
#include <hip/hip_runtime.h>
#include <hip/hip_bf16.h>

#define S_LEN 2048
#define NBATCH 2
#define DMODEL 1024
#define NHEAD 16
#define NKV 4
#define HDIM 64

typedef __attribute__((ext_vector_type(4))) float f32x4;
typedef __attribute__((ext_vector_type(8))) short s16x8;

// 0.125 (1/sqrt(dk)) * log2(e): Q pre-scale so softmax runs in exp2 domain
#define QSCALE 0.18033688011112042f

__device__ __forceinline__ unsigned short f32_bf16(float f) {
    unsigned int u = __float_as_uint(f);
    u += 0x7FFFu + ((u >> 16) & 1u);
    return (unsigned short)(u >> 16);
}

// pack two f32 -> one u32 of 2 bf16 (lo=a, hi=b) in a single VALU op (T12)
__device__ __forceinline__ unsigned int cvt_pk_bf16(float a, float b) {
    unsigned int r;
    asm("v_cvt_pk_bf16_f32 %0, %1, %2" : "=v"(r) : "v"(a), "v"(b));
    return r;
}

// ---------------- f32 -> bf16 convert + TRANSPOSE body (weights) ----------------
__device__ __forceinline__ void cvtT_body(const float* __restrict__ in,
                                          unsigned short* __restrict__ out,
                                          int N, int n_off, int bx, int by, int tid) {
    __shared__ float t[64][65];
    const int n0 = bx * 64;
    const int k0 = by * 64;
    const int r  = tid >> 4;           // 0..15
    const int c4 = (tid & 15) * 4;     // 0..60
    #pragma unroll
    for (int i = 0; i < 4; ++i) {
        const float4 v = *reinterpret_cast<const float4*>(
            in + (size_t)(k0 + i*16 + r) * N + n0 + c4);
        t[i*16 + r][c4+0] = v.x; t[i*16 + r][c4+1] = v.y;
        t[i*16 + r][c4+2] = v.z; t[i*16 + r][c4+3] = v.w;
    }
    __syncthreads();
    #pragma unroll
    for (int i = 0; i < 4; ++i) {
        const int n = i*16 + r;
        ushort4 o;
        o.x = f32_bf16(t[c4+0][n]); o.y = f32_bf16(t[c4+1][n]);
        o.z = f32_bf16(t[c4+2][n]); o.w = f32_bf16(t[c4+3][n]);
        *reinterpret_cast<ushort4*>(out + (size_t)(n_off + n0 + n) * 1024 + k0 + c4) = o;
    }
}

// ---------------- merged convert kernel: x cvt + wq/wk/wv transpose + wo ----------------
// grid 4736 blocks: [0,4096) x elementwise; [4096,4480) QKV weights; rest wo.
__global__ __launch_bounds__(256) void cvt_all_k(
    const float* __restrict__ x,  const float* __restrict__ wq,
    const float* __restrict__ wk, const float* __restrict__ wv,
    const float* __restrict__ wo,
    unsigned short* __restrict__ xb, unsigned short* __restrict__ Wqkvt,
    unsigned short* __restrict__ Wot)
{
    const int bid = blockIdx.x;
    if (bid < 4096) {
        const int i = bid * 256 + threadIdx.x;
        const float4 v = reinterpret_cast<const float4*>(x)[i];
        ushort4 r;
        r.x = f32_bf16(v.x); r.y = f32_bf16(v.y);
        r.z = f32_bf16(v.z); r.w = f32_bf16(v.w);
        reinterpret_cast<ushort4*>(xb)[i] = r;
    } else if (bid < 4480) {
        const int t  = bid - 4096;       // 384 blocks = (24 bx, 16 by)
        int bx = t % 24;
        const int by = t / 24;
        const float* in; int N, n_off;
        if (bx < 16)      { in = wq; N = 1024; n_off = 0; }
        else if (bx < 20) { in = wk; N = 256;  n_off = 1024; bx -= 16; }
        else              { in = wv; N = 256;  n_off = 1280; bx -= 20; }
        cvtT_body(in, Wqkvt, N, n_off, bx, by, threadIdx.x);
    } else {
        const int t = bid - 4480;        // 256 blocks = (16 bx, 16 by)
        cvtT_body(wo, Wot, 1024, 0, t % 16, t / 16, threadIdx.x);
    }
}

// address-space pointer types for global_load_lds
using gas_u32 = const unsigned int __attribute__((address_space(1))) *;
using las_u32 = unsigned int __attribute__((address_space(3))) *;

// ---------------- GEMM2: C[M][N] = A[M][K] @ Bt[N][K]^T, bf16, f32 acc ----------------
// (unchanged from R12 — verified; global_load_lds width=16 staging)
template<int EPI>
__global__ __launch_bounds__(256, 3) void gemm2_k(
    const unsigned short* __restrict__ A,
    const unsigned short* __restrict__ Bt,
    int N, int K,
    float* __restrict__ OutF,
    unsigned short* __restrict__ Qb,
    unsigned short* __restrict__ Kbuf,
    unsigned short* __restrict__ Vbuf)
{
    __shared__ unsigned short As[2][128 * 64];
    __shared__ unsigned short Bs[2][64 * 64];

    const int tid  = threadIdx.x;
    const int lane = tid & 63;
    const int l15  = lane & 15;
    const int l4   = lane >> 4;
    const int wave = tid >> 6;
    const int wm   = wave >> 1;
    const int wn   = wave & 1;
    const int bm   = blockIdx.y * 128;
    const int bn   = blockIdx.x * 64;

    f32x4 acc[4][2] = {};

    const int NT = K >> 6;

    #define GSTAGE(buf, k0)                                                        \
        {                                                                          \
            _Pragma("unroll")                                                      \
            for (int p = 0; p < 4; ++p) {                                          \
                const int c = p*256 + tid, r_ = c >> 3;                            \
                const int nc = (c & 7) ^ (r_ & 7);                                 \
                __builtin_amdgcn_global_load_lds(                                  \
                    (gas_u32)(A + (size_t)(bm + r_) * K + (k0) + nc*8),            \
                    (las_u32)(&As[buf][c*8]), 16, 0, 0);                           \
            }                                                                      \
            _Pragma("unroll")                                                      \
            for (int p = 0; p < 2; ++p) {                                          \
                const int c = p*256 + tid, r_ = c >> 3;                            \
                const int nc = (c & 7) ^ (r_ & 7);                                 \
                __builtin_amdgcn_global_load_lds(                                  \
                    (gas_u32)(Bt + (size_t)(bn + r_) * K + (k0) + nc*8),           \
                    (las_u32)(&Bs[buf][c*8]), 16, 0, 0);                           \
            }                                                                      \
        }

    GSTAGE(0, 0); __syncthreads();

    for (int kt = 0; kt < NT; ++kt) {
        const int cur = kt & 1;
        if (kt + 1 < NT) GSTAGE(cur ^ 1, (kt + 1) << 6);   // async into other buf
        #pragma unroll
        for (int ks = 0; ks < 2; ++ks) {
            s16x8 af[4], bfv[2];
            #pragma unroll
            for (int mi = 0; mi < 4; ++mi) {
                const int r = wm*64 + mi*16 + l15;
                af[mi] = *reinterpret_cast<const s16x8*>(
                    &As[cur][r*64 + (((ks*4 + l4) ^ (r & 7)) * 8)]);
            }
            #pragma unroll
            for (int nj = 0; nj < 2; ++nj) {
                const int r = wn*32 + nj*16 + l15;
                bfv[nj] = *reinterpret_cast<const s16x8*>(
                    &Bs[cur][r*64 + (((ks*4 + l4) ^ (r & 7)) * 8)]);
            }
            #pragma unroll
            for (int mi = 0; mi < 4; ++mi)
                #pragma unroll
                for (int nj = 0; nj < 2; ++nj)
                    acc[mi][nj] = __builtin_amdgcn_mfma_f32_16x16x32_bf16(
                        af[mi], bfv[nj], acc[mi][nj], 0, 0, 0);
        }
        __syncthreads();   // compiler drains vmcnt here (m97 structure)
    }
    #undef GSTAGE

    #pragma unroll
    for (int mi = 0; mi < 4; ++mi) {
        #pragma unroll
        for (int nj = 0; nj < 2; ++nj) {
            #pragma unroll
            for (int v = 0; v < 4; ++v) {
                const int gr = bm + wm*64 + mi*16 + l4*4 + v;
                const int gc = bn + wn*32 + nj*16 + l15;
                float val = acc[mi][nj][v];
                if (EPI == 0) {
                    OutF[(size_t)gr * N + gc] = val;
                } else {
                    const int b  = gr >> 11;
                    const int sr = gr & (S_LEN - 1);
                    const int dk = gc & 63;
                    if (bn < 1024) {                   // Q: rope + QSCALE
                        const float partner = __shfl_xor(val, 1, 64);
                        const int   jp  = dk >> 1;
                        const float inv = __expf((float)jp * (-2.0f / 64.0f) * 9.210340371976184f);
                        const int   hh  = gc >> 6;
                        float sn, cs;
                        __sincosf((float)hh * inv, &sn, &cs);
                        val = ((gc & 1) == 0) ? (val * cs - partner * sn)
                                              : (partner * sn + val * cs);
                        val *= QSCALE;
                        Qb[(((size_t)b * NHEAD + hh) * S_LEN + sr) * HDIM + dk] = f32_bf16(val);
                    } else if (bn < 1280) {            // K: rope (kv-head index)
                        const float partner = __shfl_xor(val, 1, 64);
                        const int   jp  = dk >> 1;
                        const float inv = __expf((float)jp * (-2.0f / 64.0f) * 9.210340371976184f);
                        const int   hh  = (gc - 1024) >> 6;
                        float sn, cs;
                        __sincosf((float)hh * inv, &sn, &cs);
                        val = ((gc & 1) == 0) ? (val * cs - partner * sn)
                                              : (partner * sn + val * cs);
                        Kbuf[(((size_t)b * NKV + hh) * S_LEN + sr) * HDIM + dk] = f32_bf16(val);
                    } else {                           // V: transposed [dk][s]
                        const int hh = (gc - 1280) >> 6;
                        Vbuf[(((size_t)b * NKV + hh) * HDIM + dk) * S_LEN + sr] = f32_bf16(val);
                    }
                }
            }
        }
    }
}

// ---------------- flash attention (causal, GQA), LDS-staged K/V ----------------
// R18 base (best measured: 45.1 us) + LDS row stride 72 -> 76 shorts.
// Why: stride 144B = 36 dw -> bank step 4 -> lanes l15 and l15+8 hit the SAME
// 4 banks on every ds_read_b128 (exact pairwise collision; 5.95M conflicts).
// Stride 152B = 38 dw -> bank step 6: all 16 lane starting banks distinct,
// uniform 2x coverage (the wave64-b128 floor). LDS 58,368 B -> still 2/CU.

__device__ __forceinline__ void stage_load(
    const unsigned short* __restrict__ Kp,
    const unsigned short* __restrict__ Vp,
    int kv0, int tid, s16x8& kr, s16x8& vr)
{
    const int r = tid >> 3, col = (tid & 7) * 8;   // 512 chunks of 16B per tile
    kr = *reinterpret_cast<const s16x8*>(Kp + (size_t)(kv0 + r) * HDIM + col);
    vr = *reinterpret_cast<const s16x8*>(Vp + (size_t)r * S_LEN + kv0 + col);
}

__device__ __forceinline__ void stage_write(
    unsigned short (*Ksb)[76], unsigned short (*Vsb)[76],
    int tid, const s16x8& kr, const s16x8& vr)
{
    const int r = tid >> 3, col = (tid & 7) * 8;
    *reinterpret_cast<s16x8*>(&Ksb[r][col]) = kr;
    *reinterpret_cast<s16x8*>(&Vsb[r][col]) = vr;
}

template<bool MASK>
__device__ __forceinline__ void attn_compute(
    int l15, int l4, int wloc,
    const unsigned short (*Ksb)[76], const unsigned short (*Vsb)[76],
    const s16x8 qf[2], f32x4 o[4], float& m, float& lsum,
    unsigned short (*Plds)[76])
{
    f32x4 s[4] = {};
    __builtin_amdgcn_s_setprio(1);
    #pragma unroll
    for (int c = 0; c < 4; ++c)
        #pragma unroll
        for (int ks = 0; ks < 2; ++ks) {
            const s16x8 kf = *reinterpret_cast<const s16x8*>(&Ksb[c*16 + l15][ks*32 + l4*8]);
            s[c] = __builtin_amdgcn_mfma_f32_16x16x32_bf16(kf, qf[ks], s[c], 0, 0, 0);
        }
    __builtin_amdgcn_s_setprio(0);

    if (MASK) {
        const int qloc = wloc + l15;     // q row within tile; kv within tile
        #pragma unroll
        for (int c = 0; c < 4; ++c)
            #pragma unroll
            for (int v = 0; v < 4; ++v) {
                const int kvloc = c*16 + l4*4 + v;
                s[c][v] = (kvloc <= qloc) ? s[c][v] : -1e30f;
            }
    }

    // ---- online softmax, late-shuffle defer-max; max tree allows v_max3 ----
    float mc[4];
    #pragma unroll
    for (int c = 0; c < 4; ++c)
        mc[c] = fmaxf(fmaxf(s[c][0], s[c][1]), fmaxf(s[c][2], s[c][3]));
    float mx = fmaxf(fmaxf(mc[0], mc[1]), fmaxf(mc[2], mc[3]));
    if (!__all(mx <= m + 8.0f)) {        // per-lane partial test (m group-uniform)
        mx = fmaxf(mx, __shfl_xor(mx, 16, 64));
        mx = fmaxf(mx, __shfl_xor(mx, 32, 64));
        const float mnew  = fmaxf(m, mx);
        const float scale = __builtin_amdgcn_exp2f(m - mnew);
        lsum *= scale;
        #pragma unroll
        for (int dkc = 0; dkc < 4; ++dkc) o[dkc] *= scale;
        m = mnew;
    }
    float psum = 0.0f;
    #pragma unroll
    for (int c = 0; c < 4; ++c)
        #pragma unroll
        for (int v = 0; v < 4; ++v) {
            const float p = __builtin_amdgcn_exp2f(s[c][v] - m);   // bounded by 2^8
            s[c][v] = p;
            psum += p;
        }
    lsum += psum;                        // per-lane partial; reduce at end

    // ---- P -> per-wave LDS via v_cvt_pk_bf16_f32 (1 op / f32 pair) ----
    #pragma unroll
    for (int c = 0; c < 4; ++c) {
        uint2 w;
        w.x = cvt_pk_bf16(s[c][0], s[c][1]);
        w.y = cvt_pk_bf16(s[c][2], s[c][3]);
        *reinterpret_cast<uint2*>(&Plds[l15][c*16 + l4*4]) = w;
    }
    s16x8 pb[2];
    #pragma unroll
    for (int ks = 0; ks < 2; ++ks)
        pb[ks] = *reinterpret_cast<const s16x8*>(&Plds[l15][ks*32 + l4*8]);

    __builtin_amdgcn_s_setprio(1);
    #pragma unroll
    for (int dkc = 0; dkc < 4; ++dkc)
        #pragma unroll
        for (int ks = 0; ks < 2; ++ks) {
            const s16x8 vf = *reinterpret_cast<const s16x8*>(&Vsb[dkc*16 + l15][ks*32 + l4*8]);
            o[dkc] = __builtin_amdgcn_mfma_f32_16x16x32_bf16(vf, pb[ks], o[dkc], 0, 0, 0);
        }
    __builtin_amdgcn_s_setprio(0);
}

__global__ __launch_bounds__(512, 2) void attn_k(
    const unsigned short* __restrict__ Q,
    const unsigned short* __restrict__ Kb,
    const unsigned short* __restrict__ Vt,
    unsigned short* __restrict__ Ctx)
{
    __shared__ unsigned short Ks[2][64][76];    // K tile double-buffer [kv][dk]
    __shared__ unsigned short Vs[2][64][76];    // V^T tile double-buffer [dk][kv]
    __shared__ unsigned short Plds[8][16][76];  // per-wave P tile [q16][kv64]

    const int tid  = threadIdx.x;
    const int lane = tid & 63;
    const int l15  = lane & 15;
    const int l4   = lane >> 4;
    const int wave = tid >> 6;

    // complement pairing: L and L+256 share a CU (round-robin dispatch),
    // and get q-tiles (15-p) and p -> per-CU stage total ~constant.
    const int L  = blockIdx.x;
    const int h  = L & 15;
    const int b  = (L >> 4) & 1;
    const int p  = (L >> 5) & 7;
    const int qt = (L < 256) ? (15 - p) : p;
    const int qb0 = qt * 128;

    const int g   = h >> 2;   // kv head

    const unsigned short* Qp = Q  + ((size_t)b * NHEAD + h) * S_LEN * HDIM;
    const unsigned short* Kp = Kb + ((size_t)b * NKV  + g) * S_LEN * HDIM;
    const unsigned short* Vp = Vt + ((size_t)b * NKV  + g) * HDIM * S_LEN;

    const int qb = qb0 + wave * 16;   // this wave's 16 q-rows
    const int dt = qb >> 6;           // wave's diagonal kv-tile
    const int NT = qt * 2 + 2;        // kv tiles for this block

    s16x8 qf[2];
    #pragma unroll
    for (int ks = 0; ks < 2; ++ks)
        qf[ks] = *reinterpret_cast<const s16x8*>(Qp + (size_t)(qb + l15) * HDIM + ks*32 + l4*8);

    f32x4 o[4] = {};
    float m = -1e30f, lsum = 0.0f;

    // prologue: tile 0 -> buf 0
    {
        s16x8 kr, vr;
        stage_load(Kp, Vp, 0, tid, kr, vr);
        stage_write(Ks[0], Vs[0], tid, kr, vr);
        __syncthreads();
    }

    for (int t = 0; t < NT; ++t) {
        const int cur = t & 1;
        s16x8 kr, vr;
        const bool more = (t + 1 < NT);
        if (more) stage_load(Kp, Vp, (t + 1) * 64, tid, kr, vr);   // issue early
        if (t < dt)
            attn_compute<false>(l15, l4, wave*16 - t*64 + qb0, Ks[cur], Vs[cur], qf, o, m, lsum, Plds[wave]);
        else if (t == dt)
            attn_compute<true >(l15, l4, wave*16 - t*64 + qb0, Ks[cur], Vs[cur], qf, o, m, lsum, Plds[wave]);
        // t > dt: this wave's rows are all masked out -> skip compute
        if (more) stage_write(Ks[cur ^ 1], Vs[cur ^ 1], tid, kr, vr); // vmcnt waits here
        __syncthreads();
    }

    // ---- deferred lsum cross-lane reduce + normalize + store ----
    lsum += __shfl_xor(lsum, 16, 64);
    lsum += __shfl_xor(lsum, 32, 64);
    const float inv = 1.0f / lsum;
    unsigned short* cp = Ctx + (((size_t)b * S_LEN + qb + l15) * NHEAD + h) * HDIM;
    #pragma unroll
    for (int dkc = 0; dkc < 4; ++dkc) {
        uint2 r;
        r.x = cvt_pk_bf16(o[dkc][0] * inv, o[dkc][1] * inv);
        r.y = cvt_pk_bf16(o[dkc][2] * inv, o[dkc][3] * inv);
        *reinterpret_cast<uint2*>(cp + dkc*16 + l4*4) = r;
    }
}

// ---------------- launch ----------------
// ws (ushorts): xb 4.19M | Wqkvt 1.57M | Wot 1.05M | Qb 4.19M | Kb 1.05M |
// Vbuf 1.05M = 13.1M ushorts = 25 MiB. Ctx aliases xb (dead after QKV GEMM).
extern "C" void kernel_launch(void* const* d_in, const int* in_sizes, int n_in,
                              void* d_out, int out_size, void* d_ws, size_t ws_size,
                              hipStream_t stream) {
    const float* x  = (const float*)d_in[0];
    const float* wq = (const float*)d_in[1];
    const float* wk = (const float*)d_in[2];
    const float* wv = (const float*)d_in[3];
    const float* wo = (const float*)d_in[4];
    float* out = (float*)d_out;

    const int M  = NBATCH * S_LEN;                  // 4096
    const int nX = M * DMODEL;                      // 4194304
    const int nQ = NBATCH * NHEAD * S_LEN * HDIM;   // 4194304
    const int nKV = NBATCH * NKV * S_LEN * HDIM;    // 1048576

    unsigned short* xb    = (unsigned short*)d_ws;
    unsigned short* Wqkvt = xb + nX;
    unsigned short* Wot   = Wqkvt + 1536 * 1024;
    unsigned short* Qb    = Wot + 1024 * 1024;
    unsigned short* Kb    = Qb + nQ;
    unsigned short* Vbuf  = Kb + nKV;
    unsigned short* Ctx   = xb;                     // alias

    // merged conversions: x cvt (4096 blocks) + QKV weights (384) + wo (256)
    cvt_all_k<<<dim3(4736), 256, 0, stream>>>(x, wq, wk, wv, wo, xb, Wqkvt, Wot);

    // fused QKV projection (rope, QSCALE, V^T): 24 x 32 = 768 blocks (3/CU)
    gemm2_k<1><<<dim3(1536/64, M/128), 256, 0, stream>>>(
        xb, Wqkvt, 1536, DMODEL, nullptr, Qb, Kb, Vbuf);

    attn_k<<<dim3(512, 1, 1), 512, 0, stream>>>(Qb, Kb, Vbuf, Ctx);

    // output projection -> f32: 16 x 32 = 512 blocks (2/CU)
    gemm2_k<0><<<dim3(DMODEL/64, M/128), 256, 0, stream>>>(
        Ctx, Wot, DMODEL, DMODEL, out, nullptr, nullptr, nullptr);
}

// Round 20
// 91.791 us; speedup vs baseline: 2.1619x; 2.1619x over previous
//
#include <hip/hip_runtime.h>
#include <hip/hip_bf16.h>

#define S_LEN 2048
#define NBATCH 2
#define DMODEL 1024
#define NHEAD 16
#define NKV 4
#define HDIM 64

typedef __attribute__((ext_vector_type(4))) float f32x4;
typedef __attribute__((ext_vector_type(8))) short s16x8;

// 0.125 (1/sqrt(dk)) * log2(e): Q pre-scale so softmax runs in exp2 domain
#define QSCALE 0.18033688011112042f

__device__ __forceinline__ unsigned short f32_bf16(float f) {
    unsigned int u = __float_as_uint(f);
    u += 0x7FFFu + ((u >> 16) & 1u);
    return (unsigned short)(u >> 16);
}

// pack two f32 -> one u32 of 2 bf16 (lo=a, hi=b) in a single VALU op (T12)
__device__ __forceinline__ unsigned int cvt_pk_bf16(float a, float b) {
    unsigned int r;
    asm("v_cvt_pk_bf16_f32 %0, %1, %2" : "=v"(r) : "v"(a), "v"(b));
    return r;
}

// ---------------- f32 -> bf16 convert + TRANSPOSE body (weights) ----------------
__device__ __forceinline__ void cvtT_body(const float* __restrict__ in,
                                          unsigned short* __restrict__ out,
                                          int N, int n_off, int bx, int by, int tid) {
    __shared__ float t[64][65];
    const int n0 = bx * 64;
    const int k0 = by * 64;
    const int r  = tid >> 4;           // 0..15
    const int c4 = (tid & 15) * 4;     // 0..60
    #pragma unroll
    for (int i = 0; i < 4; ++i) {
        const float4 v = *reinterpret_cast<const float4*>(
            in + (size_t)(k0 + i*16 + r) * N + n0 + c4);
        t[i*16 + r][c4+0] = v.x; t[i*16 + r][c4+1] = v.y;
        t[i*16 + r][c4+2] = v.z; t[i*16 + r][c4+3] = v.w;
    }
    __syncthreads();
    #pragma unroll
    for (int i = 0; i < 4; ++i) {
        const int n = i*16 + r;
        ushort4 o;
        o.x = f32_bf16(t[c4+0][n]); o.y = f32_bf16(t[c4+1][n]);
        o.z = f32_bf16(t[c4+2][n]); o.w = f32_bf16(t[c4+3][n]);
        *reinterpret_cast<ushort4*>(out + (size_t)(n_off + n0 + n) * 1024 + k0 + c4) = o;
    }
}

// ---------------- merged convert kernel: x cvt + wq/wk/wv transpose + wo ----------------
// grid 4736 blocks: [0,4096) x elementwise; [4096,4480) QKV weights; rest wo.
__global__ __launch_bounds__(256) void cvt_all_k(
    const float* __restrict__ x,  const float* __restrict__ wq,
    const float* __restrict__ wk, const float* __restrict__ wv,
    const float* __restrict__ wo,
    unsigned short* __restrict__ xb, unsigned short* __restrict__ Wqkvt,
    unsigned short* __restrict__ Wot)
{
    const int bid = blockIdx.x;
    if (bid < 4096) {
        const int i = bid * 256 + threadIdx.x;
        const float4 v = reinterpret_cast<const float4*>(x)[i];
        ushort4 r;
        r.x = f32_bf16(v.x); r.y = f32_bf16(v.y);
        r.z = f32_bf16(v.z); r.w = f32_bf16(v.w);
        reinterpret_cast<ushort4*>(xb)[i] = r;
    } else if (bid < 4480) {
        const int t  = bid - 4096;       // 384 blocks = (24 bx, 16 by)
        int bx = t % 24;
        const int by = t / 24;
        const float* in; int N, n_off;
        if (bx < 16)      { in = wq; N = 1024; n_off = 0; }
        else if (bx < 20) { in = wk; N = 256;  n_off = 1024; bx -= 16; }
        else              { in = wv; N = 256;  n_off = 1280; bx -= 20; }
        cvtT_body(in, Wqkvt, N, n_off, bx, by, threadIdx.x);
    } else {
        const int t = bid - 4480;        // 256 blocks = (16 bx, 16 by)
        cvtT_body(wo, Wot, 1024, 0, t % 16, t / 16, threadIdx.x);
    }
}

// address-space pointer types for global_load_lds
using gas_u32 = const unsigned int __attribute__((address_space(1))) *;
using las_u32 = unsigned int __attribute__((address_space(3))) *;

// ---------------- GEMM2: C[M][N] = A[M][K] @ Bt[N][K]^T, bf16, f32 acc ----------------
// (unchanged from R12 — verified; global_load_lds width=16 staging)
template<int EPI>
__global__ __launch_bounds__(256, 3) void gemm2_k(
    const unsigned short* __restrict__ A,
    const unsigned short* __restrict__ Bt,
    int N, int K,
    float* __restrict__ OutF,
    unsigned short* __restrict__ Qb,
    unsigned short* __restrict__ Kbuf,
    unsigned short* __restrict__ Vbuf)
{
    __shared__ unsigned short As[2][128 * 64];
    __shared__ unsigned short Bs[2][64 * 64];

    const int tid  = threadIdx.x;
    const int lane = tid & 63;
    const int l15  = lane & 15;
    const int l4   = lane >> 4;
    const int wave = tid >> 6;
    const int wm   = wave >> 1;
    const int wn   = wave & 1;
    const int bm   = blockIdx.y * 128;
    const int bn   = blockIdx.x * 64;

    f32x4 acc[4][2] = {};

    const int NT = K >> 6;

    #define GSTAGE(buf, k0)                                                        \
        {                                                                          \
            _Pragma("unroll")                                                      \
            for (int p = 0; p < 4; ++p) {                                          \
                const int c = p*256 + tid, r_ = c >> 3;                            \
                const int nc = (c & 7) ^ (r_ & 7);                                 \
                __builtin_amdgcn_global_load_lds(                                  \
                    (gas_u32)(A + (size_t)(bm + r_) * K + (k0) + nc*8),            \
                    (las_u32)(&As[buf][c*8]), 16, 0, 0);                           \
            }                                                                      \
            _Pragma("unroll")                                                      \
            for (int p = 0; p < 2; ++p) {                                          \
                const int c = p*256 + tid, r_ = c >> 3;                            \
                const int nc = (c & 7) ^ (r_ & 7);                                 \
                __builtin_amdgcn_global_load_lds(                                  \
                    (gas_u32)(Bt + (size_t)(bn + r_) * K + (k0) + nc*8),           \
                    (las_u32)(&Bs[buf][c*8]), 16, 0, 0);                           \
            }                                                                      \
        }

    GSTAGE(0, 0); __syncthreads();

    for (int kt = 0; kt < NT; ++kt) {
        const int cur = kt & 1;
        if (kt + 1 < NT) GSTAGE(cur ^ 1, (kt + 1) << 6);   // async into other buf
        #pragma unroll
        for (int ks = 0; ks < 2; ++ks) {
            s16x8 af[4], bfv[2];
            #pragma unroll
            for (int mi = 0; mi < 4; ++mi) {
                const int r = wm*64 + mi*16 + l15;
                af[mi] = *reinterpret_cast<const s16x8*>(
                    &As[cur][r*64 + (((ks*4 + l4) ^ (r & 7)) * 8)]);
            }
            #pragma unroll
            for (int nj = 0; nj < 2; ++nj) {
                const int r = wn*32 + nj*16 + l15;
                bfv[nj] = *reinterpret_cast<const s16x8*>(
                    &Bs[cur][r*64 + (((ks*4 + l4) ^ (r & 7)) * 8)]);
            }
            #pragma unroll
            for (int mi = 0; mi < 4; ++mi)
                #pragma unroll
                for (int nj = 0; nj < 2; ++nj)
                    acc[mi][nj] = __builtin_amdgcn_mfma_f32_16x16x32_bf16(
                        af[mi], bfv[nj], acc[mi][nj], 0, 0, 0);
        }
        __syncthreads();   // compiler drains vmcnt here (m97 structure)
    }
    #undef GSTAGE

    #pragma unroll
    for (int mi = 0; mi < 4; ++mi) {
        #pragma unroll
        for (int nj = 0; nj < 2; ++nj) {
            #pragma unroll
            for (int v = 0; v < 4; ++v) {
                const int gr = bm + wm*64 + mi*16 + l4*4 + v;
                const int gc = bn + wn*32 + nj*16 + l15;
                float val = acc[mi][nj][v];
                if (EPI == 0) {
                    OutF[(size_t)gr * N + gc] = val;
                } else {
                    const int b  = gr >> 11;
                    const int sr = gr & (S_LEN - 1);
                    const int dk = gc & 63;
                    if (bn < 1024) {                   // Q: rope + QSCALE
                        const float partner = __shfl_xor(val, 1, 64);
                        const int   jp  = dk >> 1;
                        const float inv = __expf((float)jp * (-2.0f / 64.0f) * 9.210340371976184f);
                        const int   hh  = gc >> 6;
                        float sn, cs;
                        __sincosf((float)hh * inv, &sn, &cs);
                        val = ((gc & 1) == 0) ? (val * cs - partner * sn)
                                              : (partner * sn + val * cs);
                        val *= QSCALE;
                        Qb[(((size_t)b * NHEAD + hh) * S_LEN + sr) * HDIM + dk] = f32_bf16(val);
                    } else if (bn < 1280) {            // K: rope (kv-head index)
                        const float partner = __shfl_xor(val, 1, 64);
                        const int   jp  = dk >> 1;
                        const float inv = __expf((float)jp * (-2.0f / 64.0f) * 9.210340371976184f);
                        const int   hh  = (gc - 1024) >> 6;
                        float sn, cs;
                        __sincosf((float)hh * inv, &sn, &cs);
                        val = ((gc & 1) == 0) ? (val * cs - partner * sn)
                                              : (partner * sn + val * cs);
                        Kbuf[(((size_t)b * NKV + hh) * S_LEN + sr) * HDIM + dk] = f32_bf16(val);
                    } else {                           // V: transposed [dk][s]
                        const int hh = (gc - 1280) >> 6;
                        Vbuf[(((size_t)b * NKV + hh) * HDIM + dk) * S_LEN + sr] = f32_bf16(val);
                    }
                }
            }
        }
    }
}

// ---------------- flash attention (causal, GQA), LDS-staged K/V ----------------
// R18-EXACT attn (best measured: 45.1 us). LDS row stride 72 shorts = 144 B:
// 16B-aligned (b128 fast path) with 2-way bank aliasing, which is free (m136).
// R19's stride-76 "fix" made rows 152 B = NOT 16B-aligned -> b128 fragmented,
// 45 -> 151 us despite zero conflicts. Aligned strides always alias 2-way;
// accept it.

__device__ __forceinline__ void stage_load(
    const unsigned short* __restrict__ Kp,
    const unsigned short* __restrict__ Vp,
    int kv0, int tid, s16x8& kr, s16x8& vr)
{
    const int r = tid >> 3, col = (tid & 7) * 8;   // 512 chunks of 16B per tile
    kr = *reinterpret_cast<const s16x8*>(Kp + (size_t)(kv0 + r) * HDIM + col);
    vr = *reinterpret_cast<const s16x8*>(Vp + (size_t)r * S_LEN + kv0 + col);
}

__device__ __forceinline__ void stage_write(
    unsigned short (*Ksb)[72], unsigned short (*Vsb)[72],
    int tid, const s16x8& kr, const s16x8& vr)
{
    const int r = tid >> 3, col = (tid & 7) * 8;
    *reinterpret_cast<s16x8*>(&Ksb[r][col]) = kr;
    *reinterpret_cast<s16x8*>(&Vsb[r][col]) = vr;
}

template<bool MASK>
__device__ __forceinline__ void attn_compute(
    int l15, int l4, int wloc,
    const unsigned short (*Ksb)[72], const unsigned short (*Vsb)[72],
    const s16x8 qf[2], f32x4 o[4], float& m, float& lsum,
    unsigned short (*Plds)[72])
{
    f32x4 s[4] = {};
    __builtin_amdgcn_s_setprio(1);
    #pragma unroll
    for (int c = 0; c < 4; ++c)
        #pragma unroll
        for (int ks = 0; ks < 2; ++ks) {
            const s16x8 kf = *reinterpret_cast<const s16x8*>(&Ksb[c*16 + l15][ks*32 + l4*8]);
            s[c] = __builtin_amdgcn_mfma_f32_16x16x32_bf16(kf, qf[ks], s[c], 0, 0, 0);
        }
    __builtin_amdgcn_s_setprio(0);

    if (MASK) {
        const int qloc = wloc + l15;     // q row within tile; kv within tile
        #pragma unroll
        for (int c = 0; c < 4; ++c)
            #pragma unroll
            for (int v = 0; v < 4; ++v) {
                const int kvloc = c*16 + l4*4 + v;
                s[c][v] = (kvloc <= qloc) ? s[c][v] : -1e30f;
            }
    }

    // ---- online softmax, late-shuffle defer-max; max tree allows v_max3 ----
    float mc[4];
    #pragma unroll
    for (int c = 0; c < 4; ++c)
        mc[c] = fmaxf(fmaxf(s[c][0], s[c][1]), fmaxf(s[c][2], s[c][3]));
    float mx = fmaxf(fmaxf(mc[0], mc[1]), fmaxf(mc[2], mc[3]));
    if (!__all(mx <= m + 8.0f)) {        // per-lane partial test (m group-uniform)
        mx = fmaxf(mx, __shfl_xor(mx, 16, 64));
        mx = fmaxf(mx, __shfl_xor(mx, 32, 64));
        const float mnew  = fmaxf(m, mx);
        const float scale = __builtin_amdgcn_exp2f(m - mnew);
        lsum *= scale;
        #pragma unroll
        for (int dkc = 0; dkc < 4; ++dkc) o[dkc] *= scale;
        m = mnew;
    }
    float psum = 0.0f;
    #pragma unroll
    for (int c = 0; c < 4; ++c)
        #pragma unroll
        for (int v = 0; v < 4; ++v) {
            const float p = __builtin_amdgcn_exp2f(s[c][v] - m);   // bounded by 2^8
            s[c][v] = p;
            psum += p;
        }
    lsum += psum;                        // per-lane partial; reduce at end

    // ---- P -> per-wave LDS via v_cvt_pk_bf16_f32 (1 op / f32 pair) ----
    #pragma unroll
    for (int c = 0; c < 4; ++c) {
        uint2 w;
        w.x = cvt_pk_bf16(s[c][0], s[c][1]);
        w.y = cvt_pk_bf16(s[c][2], s[c][3]);
        *reinterpret_cast<uint2*>(&Plds[l15][c*16 + l4*4]) = w;
    }
    s16x8 pb[2];
    #pragma unroll
    for (int ks = 0; ks < 2; ++ks)
        pb[ks] = *reinterpret_cast<const s16x8*>(&Plds[l15][ks*32 + l4*8]);

    __builtin_amdgcn_s_setprio(1);
    #pragma unroll
    for (int dkc = 0; dkc < 4; ++dkc)
        #pragma unroll
        for (int ks = 0; ks < 2; ++ks) {
            const s16x8 vf = *reinterpret_cast<const s16x8*>(&Vsb[dkc*16 + l15][ks*32 + l4*8]);
            o[dkc] = __builtin_amdgcn_mfma_f32_16x16x32_bf16(vf, pb[ks], o[dkc], 0, 0, 0);
        }
    __builtin_amdgcn_s_setprio(0);
}

__global__ __launch_bounds__(512, 2) void attn_k(
    const unsigned short* __restrict__ Q,
    const unsigned short* __restrict__ Kb,
    const unsigned short* __restrict__ Vt,
    unsigned short* __restrict__ Ctx)
{
    __shared__ unsigned short Ks[2][64][72];    // K tile double-buffer [kv][dk]
    __shared__ unsigned short Vs[2][64][72];    // V^T tile double-buffer [dk][kv]
    __shared__ unsigned short Plds[8][16][72];  // per-wave P tile [q16][kv64]

    const int tid  = threadIdx.x;
    const int lane = tid & 63;
    const int l15  = lane & 15;
    const int l4   = lane >> 4;
    const int wave = tid >> 6;

    // complement pairing: L and L+256 share a CU (round-robin dispatch),
    // and get q-tiles (15-p) and p -> per-CU stage total ~constant.
    const int L  = blockIdx.x;
    const int h  = L & 15;
    const int b  = (L >> 4) & 1;
    const int p  = (L >> 5) & 7;
    const int qt = (L < 256) ? (15 - p) : p;
    const int qb0 = qt * 128;

    const int g   = h >> 2;   // kv head

    const unsigned short* Qp = Q  + ((size_t)b * NHEAD + h) * S_LEN * HDIM;
    const unsigned short* Kp = Kb + ((size_t)b * NKV  + g) * S_LEN * HDIM;
    const unsigned short* Vp = Vt + ((size_t)b * NKV  + g) * HDIM * S_LEN;

    const int qb = qb0 + wave * 16;   // this wave's 16 q-rows
    const int dt = qb >> 6;           // wave's diagonal kv-tile
    const int NT = qt * 2 + 2;        // kv tiles for this block

    s16x8 qf[2];
    #pragma unroll
    for (int ks = 0; ks < 2; ++ks)
        qf[ks] = *reinterpret_cast<const s16x8*>(Qp + (size_t)(qb + l15) * HDIM + ks*32 + l4*8);

    f32x4 o[4] = {};
    float m = -1e30f, lsum = 0.0f;

    // prologue: tile 0 -> buf 0
    {
        s16x8 kr, vr;
        stage_load(Kp, Vp, 0, tid, kr, vr);
        stage_write(Ks[0], Vs[0], tid, kr, vr);
        __syncthreads();
    }

    for (int t = 0; t < NT; ++t) {
        const int cur = t & 1;
        s16x8 kr, vr;
        const bool more = (t + 1 < NT);
        if (more) stage_load(Kp, Vp, (t + 1) * 64, tid, kr, vr);   // issue early
        if (t < dt)
            attn_compute<false>(l15, l4, wave*16 - t*64 + qb0, Ks[cur], Vs[cur], qf, o, m, lsum, Plds[wave]);
        else if (t == dt)
            attn_compute<true >(l15, l4, wave*16 - t*64 + qb0, Ks[cur], Vs[cur], qf, o, m, lsum, Plds[wave]);
        // t > dt: this wave's rows are all masked out -> skip compute
        if (more) stage_write(Ks[cur ^ 1], Vs[cur ^ 1], tid, kr, vr); // vmcnt waits here
        __syncthreads();
    }

    // ---- deferred lsum cross-lane reduce + normalize + store ----
    lsum += __shfl_xor(lsum, 16, 64);
    lsum += __shfl_xor(lsum, 32, 64);
    const float inv = 1.0f / lsum;
    unsigned short* cp = Ctx + (((size_t)b * S_LEN + qb + l15) * NHEAD + h) * HDIM;
    #pragma unroll
    for (int dkc = 0; dkc < 4; ++dkc) {
        uint2 r;
        r.x = cvt_pk_bf16(o[dkc][0] * inv, o[dkc][1] * inv);
        r.y = cvt_pk_bf16(o[dkc][2] * inv, o[dkc][3] * inv);
        *reinterpret_cast<uint2*>(cp + dkc*16 + l4*4) = r;
    }
}

// ---------------- launch ----------------
// ws (ushorts): xb 4.19M | Wqkvt 1.57M | Wot 1.05M | Qb 4.19M | Kb 1.05M |
// Vbuf 1.05M = 13.1M ushorts = 25 MiB. Ctx aliases xb (dead after QKV GEMM).
extern "C" void kernel_launch(void* const* d_in, const int* in_sizes, int n_in,
                              void* d_out, int out_size, void* d_ws, size_t ws_size,
                              hipStream_t stream) {
    const float* x  = (const float*)d_in[0];
    const float* wq = (const float*)d_in[1];
    const float* wk = (const float*)d_in[2];
    const float* wv = (const float*)d_in[3];
    const float* wo = (const float*)d_in[4];
    float* out = (float*)d_out;

    const int M  = NBATCH * S_LEN;                  // 4096
    const int nX = M * DMODEL;                      // 4194304
    const int nQ = NBATCH * NHEAD * S_LEN * HDIM;   // 4194304
    const int nKV = NBATCH * NKV * S_LEN * HDIM;    // 1048576

    unsigned short* xb    = (unsigned short*)d_ws;
    unsigned short* Wqkvt = xb + nX;
    unsigned short* Wot   = Wqkvt + 1536 * 1024;
    unsigned short* Qb    = Wot + 1024 * 1024;
    unsigned short* Kb    = Qb + nQ;
    unsigned short* Vbuf  = Kb + nKV;
    unsigned short* Ctx   = xb;                     // alias

    // merged conversions: x cvt (4096 blocks) + QKV weights (384) + wo (256)
    cvt_all_k<<<dim3(4736), 256, 0, stream>>>(x, wq, wk, wv, wo, xb, Wqkvt, Wot);

    // fused QKV projection (rope, QSCALE, V^T): 24 x 32 = 768 blocks (3/CU)
    gemm2_k<1><<<dim3(1536/64, M/128), 256, 0, stream>>>(
        xb, Wqkvt, 1536, DMODEL, nullptr, Qb, Kb, Vbuf);

    attn_k<<<dim3(512, 1, 1), 512, 0, stream>>>(Qb, Kb, Vbuf, Ctx);

    // output projection -> f32: 16 x 32 = 512 blocks (2/CU)
    gemm2_k<0><<<dim3(DMODEL/64, M/128), 256, 0, stream>>>(
        Ctx, Wot, DMODEL, DMODEL, out, nullptr, nullptr, nullptr);
}